// Round 8
// baseline (154.102 us; speedup 1.0000x reference)
//
#include <hip/hip_runtime.h>
#include <hip/hip_bf16.h>

// ---------------------------------------------------------------------------
// InferCellV2 R13b: B weights via registers from L1/L2; LDS carries A only.
// (R13 resubmit: uint4 is a HIP_vector_type struct whose operator= can't
// bind an addrspace(1) reference; use a native clang ext_vector u32x4.)
// R12 discriminator result: explicit reg pipeline bought +2.5us only ->
// Branch P confirmed: LDS-pipe THROUGHPUT bound (64 ds_read_b128/step ~768cyc
// vs 310cyc MFMA -> MfmaUtil pinned ~22%). LDS traffic = half A (irreducible,
// waves own disjoint pixels) + half B (pure broadcast waste: 8 waves re-read
// the SAME 8KB tap). R13 routes B around the LDS pipe: per-tap register
// ping-pong Bb[2][8] (64 VGPR; parity static under full unroll; liveness
// bounded by ping-pong WAR dep and NEVER crosses a barrier - the R7/R10/R11
// spill pattern was live-across-barrier, avoided here). wt re-laid-out
// fragment-major ([l][tap][f=q*4+n][lane]*16B) -> each B load is one
// coalesced 1KB global_load_dwordx4; tap read by 8 waves within ~300cyc ->
// 1 L2 miss + 7 L1 hits (wt 72-216KB/kernel, L2-resident). LDS = A-only
// 78336B. Pipes now parallel: LDS-A 768cyc/tap/CU, VMEM-B ~1024, MFMA 310
// -> bound ~1024 vs 1536 -> conv core ~1.5x.
// Kept verified: A layout/staging/swizzle, oc-permuted acc->true-oc mapping
// (acc col n*16+l15 = true oc l15*4+n) + both epilogues, pre_kernel image
// paths, __launch_bounds__(512,1), grid 256 = 1 block/CU.
// Layouts:
//   activations: zero-padded NHWC bf16 [B][34][34][64], chunk cb of pixel p
//     at p*128 + ((cb^(p&7))*16)  [verified conflict-free R3/R6]
//   weights (NEW): elem (l,t,o,i): os=(o&3)*16+(o>>2); n=os>>4, l15=os&15;
//     q=i>>5, quad=(i>>3)&3, e=i&7; lane=quad*16+l15;
//     wt[(l*9+t)*4096 + (q*4+n)*512 + lane*8 + e]
// Wave tile 64px x 64oc = 4x4 MFMA 16x16x32, 64 acc VGPRs.
// ---------------------------------------------------------------------------

typedef __bf16 bf16x8 __attribute__((ext_vector_type(8)));
typedef float floatx4 __attribute__((ext_vector_type(4)));
typedef unsigned int uint32;
typedef uint32 u32x4 __attribute__((ext_vector_type(4)));

#define PADW 34
#define PIMG (PADW * PADW)
#define ROWB (PADW * 64 * 2)        // 4352 B per padded NHWC row
#define A_LDS (18 * ROWB)           // 78336 (16 out rows + 2 halo)
#define A_CHUNKS (A_LDS / 16)       // 4896 = 9*512 + 288
#define A_TAIL (A_CHUNKS - 9 * 512) // 288
#define TAPB (64 * 64 * 2)          // 8192 B per weight tap
#define SMEM_BYTES A_LDS            // A only: 78336

__device__ __forceinline__ void gld16(const char* g, char* l) {
    __builtin_amdgcn_global_load_lds(
        (const __attribute__((address_space(1))) uint32*)g,
        (__attribute__((address_space(3))) uint32*)l, 16, 0, 0);
}

// ---------------- fused pre-pass: prep_weights + zero_halo + relu_pad -------
__global__ __launch_bounds__(256) void pre_kernel(
    const float* __restrict__ in, const float* __restrict__ a1,
    const float* __restrict__ a2, const float* __restrict__ W,
    __hip_bfloat16* __restrict__ wt, __hip_bfloat16* __restrict__ r0,
    __hip_bfloat16* __restrict__ r1, __hip_bfloat16* __restrict__ r2) {
    __shared__ float tile[32][65];
    int blk = blockIdx.x;
    int tid = threadIdx.x;

    if (blk < 864) {                 // ---- weights: fold scale + frag-major
        int idx = blk * 256 + tid;   // 6*9*64*64 = 221184 exact
        int i = idx & 63;            // true in-ch
        int o = (idx >> 6) & 63;     // true out-ch
        int rest = idx >> 12;
        int t = rest % 9;
        int l = rest / 9;
        int ji = i >> 3, jo = o >> 3;
        float ain = 0.f, aout = 0.f;
#pragma unroll
        for (int j = 0; j < 8; ++j) {
            ain  += (j >= ji) ? a1[j] : 0.f;
            aout += (j >= jo) ? a2[j] : 0.f;
        }
        float v = W[(size_t)((l * 64 + o) * 64 + i) * 9 + t] * ain * aout;
        // oc-permute (acc col n*16+l15 -> true oc l15*4+n), then frag-major:
        int os = ((o & 3) << 4) + (o >> 2);
        int n  = os >> 4, c15 = os & 15;
        int q  = i >> 5, quad = (i >> 3) & 3, e = i & 7;
        int ln = (quad << 4) + c15;
        size_t idx2 = (size_t)(l * 9 + t) * 4096 + (((q << 2) + n) << 9) +
                      (ln << 3) + e;
        wt[idx2] = __float2bfloat16(v);
    } else if (blk < 992) {          // ---- zero halo ring, image b
        int b = blk - 864;
        __hip_bfloat16* bufs[3] = {r0, r1, r2};
#pragma unroll
        for (int f = 0; f < 3; ++f) {
            uint32* buf = (uint32*)(bufs[f] + (size_t)b * PIMG * 64);
            for (int idx = tid; idx < 132 * 32; idx += 256) {
                int slot = idx >> 5, u = idx & 31;
                int yy, xx;
                if (slot < 34)      { yy = 0;  xx = slot; }
                else if (slot < 68) { yy = 33; xx = slot - 34; }
                else { int s2 = slot - 68; yy = 1 + (s2 >> 1); xx = (s2 & 1) * 33; }
                buf[(size_t)(yy * PADW + xx) * 32 + u] = 0u;
            }
        }
    } else {                         // ---- relu(x) -> padded swizzled NHWC
        int rb = blk - 992;
        int b = rb >> 5, y = rb & 31;
        int x = tid & 31, c0 = tid >> 5;
        const float* ip = in + ((size_t)b * 64 * 32 + y) * 32 + x;
#pragma unroll
        for (int cc = 0; cc < 8; ++cc) {
            int c = cc * 8 + c0;
            tile[x][c] = fmaxf(ip[(size_t)c * 1024], 0.f);
        }
        __syncthreads();
        // one 16B chunk store per thread: thread = (pixel xq, chunk j);
        // chunk j of pixel p lives at p*128 + (j^(p&7))*16.
        int j = tid & 7, xq = tid >> 3;
        int p = (b * PADW + y + 1) * PADW + 1 + xq;
        alignas(16) __hip_bfloat16 hv[8];
#pragma unroll
        for (int k = 0; k < 8; ++k)
            hv[k] = __float2bfloat16(tile[xq][j * 8 + k]);
        *(uint4*)((char*)r0 + (size_t)p * 128 + ((j ^ (p & 7)) << 4)) =
            *(const uint4*)hv;
    }
}

// ---------------- conv stage: A from LDS, B from registers -----------------
// Block: image b = blk>>1, strip y0 = (blk&1)*16. Wave wv: rows y0+2wv,+1.
// A-frag: l15 = px, quad*8+q*32 = in-ch. B-frag f=q*4+n: coalesced 1KB load.
// C/D: M(pixel) = quad*4+r; acc col n*16+l15 = TRUE oc l15*4+n.
template <int NSRC, bool FINAL>
__global__ __launch_bounds__(512, 1) void conv_stage(
    const __hip_bfloat16* __restrict__ s0,
    const __hip_bfloat16* __restrict__ s1,
    const __hip_bfloat16* __restrict__ s2,
    const __hip_bfloat16* __restrict__ wt,
    void* __restrict__ dstv, int l0) {
    extern __shared__ char smem[];               // A only: 78336 B
    int tid = threadIdx.x;
    int wv = tid >> 6, lane = tid & 63;
    int quad = lane >> 4, l15 = lane & 15;
    int blk = blockIdx.x;
    int b = blk >> 1, y0 = (blk & 1) << 4;

    const char* srcs[3] = {(const char*)s0, (const char*)s1, (const char*)s2};
    const char* gW = (const char*)wt + (size_t)l0 * 9 * (size_t)TAPB;
    const size_t aOff = (size_t)(b * PADW + y0) * PADW * 128;

    auto stage_A = [&](int s) {      // 18 padded rows, linear 16B DMA copy
        const char* gA = srcs[s] + aOff;
#pragma unroll
        for (int it = 0; it < 10; ++it) {
            int c = it * 512 + tid;
            if (it < 9 || tid < A_TAIL)
                gld16(gA + (size_t)c * 16, smem + (it * 512 + wv * 64) * 16);
        }
    };

    floatx4 acc[4][4];
#pragma unroll
    for (int m = 0; m < 4; ++m)
#pragma unroll
        for (int n = 0; n < 4; ++n) acc[m][n] = (floatx4){0.f, 0.f, 0.f, 0.f};

    stage_A(0);
    __syncthreads();                 // A(src0) resident

#pragma unroll 1
    for (int s = 0; s < NSRC; ++s) {
        const char* gWs = gW + (size_t)s * 9 * TAPB;
        // per-tap B frags, coalesced 1KB loads, register ping-pong.
        // Liveness bounded by WAR on the parity buffer; never crosses a
        // barrier (R7/R10/R11 spill lesson).
        u32x4 Bb[2][8];
        auto ldBg = [&](int t, int par) {
#pragma unroll
            for (int f = 0; f < 8; ++f)
                Bb[par][f] = *(const __attribute__((address_space(1))) u32x4*)
                    (gWs + (size_t)t * TAPB + (f << 10) + (lane << 4));
        };
        ldBg(0, 0);
#pragma unroll
        for (int t = 0; t < 9; ++t) {            // full unroll: par static
            const int par = t & 1;
            if (t < 8) ldBg(t + 1, par ^ 1);     // next tap under this MFMA
            const int ky = t / 3, kx = t % 3;
#pragma unroll
            for (int q = 0; q < 2; ++q) {
                bf16x8 Af[4];
#pragma unroll
                for (int m = 0; m < 4; ++m) {
                    int arow = 2 * wv + (m >> 1) + ky;      // LDS row 0..17
                    int apx  = ((m & 1) << 4) + l15 + kx;   // 0..33
                    int R = b * PADW + y0 + arow;           // global pad row
                    int slot = ((q << 2) + quad) ^ ((2 * R + apx) & 7);
                    Af[m] = *(const bf16x8*)(smem + arow * ROWB +
                                             apx * 128 + slot * 16);
                }
                __builtin_amdgcn_s_setprio(1);
#pragma unroll
                for (int n = 0; n < 4; ++n) {
                    bf16x8 Bf = __builtin_bit_cast(bf16x8,
                                                   Bb[par][(q << 2) + n]);
#pragma unroll
                    for (int m = 0; m < 4; ++m)
                        acc[m][n] = __builtin_amdgcn_mfma_f32_16x16x32_bf16(
                            Af[m], Bf, acc[m][n], 0, 0, 0);
                }
                __builtin_amdgcn_s_setprio(0);
            }
        }
        if (s + 1 < NSRC) {          // source switch: restage A only
            __syncthreads();         // all waves done reading src s A
            stage_A(s + 1);
            __syncthreads();         // staging drained (vmcnt0 via barrier)
        }
    }

    // Epilogue. M(pixel)=quad*4+r (+16 odd m-tile); acc col c=n*16+l15 holds
    // TRUE oc l15*4+n (wt oc-permuted) -> lane's 4 n-values are contiguous.
    if (FINAL) {
        float* out = (float*)dstv;   // fp32 NCHW [128][64][32][32]
#pragma unroll
        for (int m = 0; m < 4; ++m) {
            int row = y0 + 2 * wv + (m >> 1);
#pragma unroll
            for (int n = 0; n < 4; ++n) {
                int o = (l15 << 2) + n;                     // TRUE oc
                *(floatx4*)(out + (((size_t)b * 64 + o) * 32 + row) * 32 +
                            ((m & 1) << 4) + (quad << 2)) = acc[m][n];
            }
        }
    } else {
        __hip_bfloat16* out = (__hip_bfloat16*)dstv;  // relu -> swizzled NHWC
#pragma unroll
        for (int m = 0; m < 4; ++m) {
            int row = y0 + 2 * wv + (m >> 1);
#pragma unroll
            for (int r = 0; r < 4; ++r) {
                int x = ((m & 1) << 4) + (quad << 2) + r;
                int p = (b * PADW + row + 1) * PADW + x + 1;
                alignas(8) __hip_bfloat16 hv[4];
#pragma unroll
                for (int n = 0; n < 4; ++n)
                    hv[n] = __float2bfloat16(fmaxf(acc[m][n][r], 0.f));
                // true chs l15*4..+3 = storage chunk l15>>1, half (l15&1)
                char* d8 = (char*)out + (size_t)p * 128 +
                           ((((l15 >> 1) ^ (p & 7)) << 4) + ((l15 & 1) << 3));
                *(uint2*)d8 = *(const uint2*)hv;
            }
        }
    }
}

// ---------------------------------------------------------------------------
extern "C" void kernel_launch(void* const* d_in, const int* in_sizes, int n_in,
                              void* d_out, int out_size, void* d_ws,
                              size_t ws_size, hipStream_t stream) {
    const float* inputs  = (const float*)d_in[0];
    const float* alphas1 = (const float*)d_in[1];
    const float* alphas2 = (const float*)d_in[2];
    const float* W       = (const float*)d_in[3];
    char* ws = (char*)d_ws;

    __hip_bfloat16* wt = (__hip_bfloat16*)(ws);                     // 442 KB
    __hip_bfloat16* r0 = (__hip_bfloat16*)(ws + ((size_t)1 << 20)); // 18.9 MB
    __hip_bfloat16* r1 = (__hip_bfloat16*)(ws + ((size_t)20 << 20));
    __hip_bfloat16* r2 = (__hip_bfloat16*)(ws + ((size_t)40 << 20));
    float* out = (float*)d_out;

    // Opt-in to >64KB dynamic LDS (idempotent; harmless under graph capture).
    (void)hipFuncSetAttribute((const void*)conv_stage<1, false>,
                              hipFuncAttributeMaxDynamicSharedMemorySize,
                              SMEM_BYTES);
    (void)hipFuncSetAttribute((const void*)conv_stage<2, false>,
                              hipFuncAttributeMaxDynamicSharedMemorySize,
                              SMEM_BYTES);
    (void)hipFuncSetAttribute((const void*)conv_stage<3, true>,
                              hipFuncAttributeMaxDynamicSharedMemorySize,
                              SMEM_BYTES);

    pre_kernel<<<864 + 128 + 4096, 256, 0, stream>>>(inputs, alphas1, alphas2,
                                                     W, wt, r0, r1, r2);
    conv_stage<1, false><<<256, 512, SMEM_BYTES, stream>>>(r0, r1, r2, wt,
                                                           (void*)r1, 0);
    conv_stage<2, false><<<256, 512, SMEM_BYTES, stream>>>(r0, r1, r2, wt,
                                                           (void*)r2, 1);
    conv_stage<3, true ><<<256, 512, SMEM_BYTES, stream>>>(r0, r1, r2, wt,
                                                           (void*)out, 3);
}